// Round 2
// baseline (661.048 us; speedup 1.0000x reference)
//
#include <hip/hip_runtime.h>
#include <cstdint>
#include <cstddef>

typedef _Float16 f16;
typedef _Float16 f16x8 __attribute__((ext_vector_type(8)));
typedef float f32x4 __attribute__((ext_vector_type(4)));

#define LOG2E 1.4426950408889634f

__device__ __forceinline__ float fast_rcp(float x) { return __builtin_amdgcn_rcpf(x); }
__device__ __forceinline__ float sigmoid_f(float x) { return fast_rcp(1.f + exp2f(-LOG2E * x)); }
__device__ __forceinline__ float tanh_f(float x)    { return 1.f - 2.f * fast_rcp(1.f + exp2f(2.f * LOG2E * x)); }
__device__ __forceinline__ float elu_f(float x)     { return x > 0.f ? x : exp2f(LOG2E * x) - 1.f; }

// ---------------------------------------------------------------------------
// Weight pre-pack: fp32 -> fp16 MFMA B-fragment order.
// B-frag (16x16x32): lane l holds col j = jt*16 + (l&15), k = kt*32 + (l>>4)*8 + e
// wpkh: [48 jt][8 kt][64 l][8 e]   from w_hh[768][256]   (w_hh[j][k], contiguous k)
// wpk1: [8 kt][4 jt][64][8]        from w1[256][64]      (w1[k][j])
// wpk2: [2 kt][4 jt][64][8]        from w2[64][64]
// wpk3: [2 kt][38 jt][64][8]       from w3[64][601] (pad j>=601 with 0)
// ---------------------------------------------------------------------------
__global__ void pack_weights(const float* __restrict__ w_hh, const float* __restrict__ w1,
                             const float* __restrict__ w2, const float* __restrict__ w3,
                             f16* __restrict__ wpkh, f16* __restrict__ wpk1,
                             f16* __restrict__ wpk2, f16* __restrict__ wpk3) {
    int s = blockIdx.x * 256 + threadIdx.x;   // 32000 slots total
    if (s < 24576) {                            // wpkh
        int l = s & 63, kt = (s >> 6) & 7, jt = s >> 9;
        int j = jt * 16 + (l & 15), k = kt * 32 + (l >> 4) * 8;
        const float* src = w_hh + (size_t)j * 256 + k;
        f16x8 v;
        #pragma unroll
        for (int e = 0; e < 8; ++e) v[e] = (f16)src[e];
        *(f16x8*)(wpkh + (size_t)s * 8) = v;
    } else if (s < 26624) {                     // wpk1
        int q = s - 24576;
        int l = q & 63, jt = (q >> 6) & 3, kt = q >> 8;
        int j = jt * 16 + (l & 15), k = kt * 32 + (l >> 4) * 8;
        f16x8 v;
        #pragma unroll
        for (int e = 0; e < 8; ++e) v[e] = (f16)w1[(size_t)(k + e) * 64 + j];
        *(f16x8*)(wpk1 + (size_t)q * 8) = v;
    } else if (s < 27136) {                     // wpk2
        int q = s - 26624;
        int l = q & 63, jt = (q >> 6) & 3, kt = q >> 8;
        int j = jt * 16 + (l & 15), k = kt * 32 + (l >> 4) * 8;
        f16x8 v;
        #pragma unroll
        for (int e = 0; e < 8; ++e) v[e] = (f16)w2[(size_t)(k + e) * 64 + j];
        *(f16x8*)(wpk2 + (size_t)q * 8) = v;
    } else if (s < 32000) {                     // wpk3
        int q = s - 27136;
        int l = q & 63, rr = q >> 6;
        int jt = rr % 38, kt = rr / 38;
        int j = jt * 16 + (l & 15), k = kt * 32 + (l >> 4) * 8;
        f16x8 v;
        #pragma unroll
        for (int e = 0; e < 8; ++e) v[e] = (j < 601) ? (f16)w3[(size_t)(k + e) * 601 + j] : (f16)0.f;
        *(f16x8*)(wpk3 + (size_t)q * 8) = v;
    }
}

// ---------------------------------------------------------------------------
// GRU scan. One block = 16 batch rows, 512 threads (8 waves), 64 timesteps.
// w_hh held in registers as 48 fp16 B-frags/lane (192 VGPR). Wave wid owns
// output cols {wid*32 .. wid*32+31} of each of the 3 gates.
// h: double-buffered fp16 in LDS (MFMA A input) + fp32 in regs (z*h term).
// acc init: r,z gates = b_ih+b_hh (folded); n gate = b_hh only (b_ih must
// stay outside the r*(...) product per PyTorch GRU semantics).
// ---------------------------------------------------------------------------
template <int ALIGNED>
__global__ __launch_bounds__(512, 2)
void gru_kernel(const float* __restrict__ x, const float* __restrict__ h0,
                const float* __restrict__ w_ih, const float* __restrict__ b_ih,
                const float* __restrict__ b_hh, const f16* __restrict__ wpkh,
                char* __restrict__ ys_base, float* __restrict__ h1_out) {
    __shared__ f16 h_lds[2][16][264];   // pad 256->264 (16B) to spread banks
    __shared__ float x_lds[64][16];

    const int tid = threadIdx.x, lane = tid & 63, wid = tid >> 6;
    const int l15 = lane & 15, lg = lane >> 4;
    const int b0 = blockIdx.x * 16;
    const long STRIDE = ALIGNED ? 512 : 2404;

    // --- persistent W fragments (static-indexed: must stay in VGPRs) ---
    f16x8 wf[6][8];
    #pragma unroll
    for (int g = 0; g < 3; ++g)
        #pragma unroll
        for (int sub = 0; sub < 2; ++sub) {
            int jt = g * 16 + wid * 2 + sub;
            #pragma unroll
            for (int kt = 0; kt < 8; ++kt)
                wf[g * 2 + sub][kt] = *(const f16x8*)(wpkh + (((size_t)jt * 8 + kt) * 64 + lane) * 8);
        }

    // per-lane input-path scalars. bacc = acc-init bias per (gate,sub):
    // r,z: b_ih+b_hh ; n: b_hh. bin = b_ih of n gate (added outside).
    float wi[3][2], bacc[3][2], bin[2];
    #pragma unroll
    for (int g = 0; g < 3; ++g)
        #pragma unroll
        for (int sub = 0; sub < 2; ++sub) {
            int j = g * 256 + wid * 32 + sub * 16 + l15;
            wi[g][sub] = w_ih[j];
            bacc[g][sub] = (g < 2) ? (b_ih[j] + b_hh[j]) : b_hh[j];
            if (g == 2) bin[sub] = b_ih[j];
        }

    // fp32 h state for this lane's 8 (row,col) cells
    float hp[2][4];
    #pragma unroll
    for (int sub = 0; sub < 2; ++sub)
        #pragma unroll
        for (int r = 0; r < 4; ++r)
            hp[sub][r] = h0[(size_t)(b0 + lg * 4 + r) * 256 + wid * 32 + sub * 16 + l15];

    // stage h0 -> h_lds[0] (fp16) and full x slice -> x_lds
    {
        int row = tid >> 5, k0 = (tid & 31) * 8;
        const float* src = h0 + (size_t)(b0 + row) * 256 + k0;
        f16x8 v;
        #pragma unroll
        for (int e = 0; e < 8; ++e) v[e] = (f16)src[e];
        *(f16x8*)&h_lds[0][row][k0] = v;
        #pragma unroll
        for (int i = 0; i < 2; ++i) {
            int n = tid + i * 512, tt = n >> 4, bb = n & 15;
            x_lds[tt][bb] = x[(size_t)tt * 2048 + b0 + bb];
        }
    }
    __syncthreads();

    for (int t = 0; t < 64; ++t) {
        const int cur = t & 1, nxt = cur ^ 1;

        // gh = h @ w_hh^T (+ folded biases)
        f32x4 acc[6];
        #pragma unroll
        for (int i = 0; i < 6; ++i) {
            float b = bacc[i >> 1][i & 1];
            acc[i] = (f32x4){b, b, b, b};
        }
        #pragma unroll
        for (int kt = 0; kt < 8; ++kt) {
            f16x8 a = *(const f16x8*)&h_lds[cur][l15][kt * 32 + lg * 8];
            #pragma unroll
            for (int i = 0; i < 6; ++i)
                acc[i] = __builtin_amdgcn_mfma_f32_16x16x32_f16(a, wf[i][kt], acc[i], 0, 0, 0);
        }

        // gates (lane-local: R/Z/N tiles share the C/D layout)
        f32x4 xv4 = *(const f32x4*)&x_lds[t][lg * 4];
        #pragma unroll
        for (int sub = 0; sub < 2; ++sub)
            #pragma unroll
            for (int r = 0; r < 4; ++r) {
                float xv = xv4[r];
                float rg = sigmoid_f(xv * wi[0][sub] + acc[0 + sub][r]);
                float zg = sigmoid_f(xv * wi[1][sub] + acc[2 + sub][r]);
                float ng = tanh_f(xv * wi[2][sub] + bin[sub] + rg * acc[4 + sub][r]);
                float hn = ng + zg * (hp[sub][r] - ng);
                hp[sub][r] = hn;
                h_lds[nxt][lg * 4 + r][wid * 32 + sub * 16 + l15] = (f16)hn;
            }
        __syncthreads();

        // coalesced ys write from h_lds[nxt].
        // Safe: next overwrite of this buffer is step t+2's gate phase, which
        // every wave reaches only after step t+1's barrier, i.e. after all
        // waves completed this read (program order within each wave).
        {
            int row = tid >> 5, k0 = (tid & 31) * 8;
            f16x8 v = *(const f16x8*)&h_lds[nxt][row][k0];
            char* dst = ys_base + (size_t)(t * 2048 + b0 + row) * STRIDE + (size_t)k0 * 2;
            if (ALIGNED) {
                *(f16x8*)dst = v;
            } else {
                const uint32_t* u = (const uint32_t*)&v;
                uint32_t* d = (uint32_t*)dst;
                d[0] = u[0]; d[1] = u[1]; d[2] = u[2]; d[3] = u[3];
            }
        }
    }

    // h_last (fp32) -> d_out tail
    #pragma unroll
    for (int sub = 0; sub < 2; ++sub)
        #pragma unroll
        for (int r = 0; r < 4; ++r)
            h1_out[(size_t)(b0 + lg * 4 + r) * 256 + wid * 32 + sub * 16 + l15] = hp[sub][r];
}

// ---------------------------------------------------------------------------
// MLP: rows = T*B = 131072. Block = 4 independent waves x 16 rows.
// ys(fp16) -> elu(@w1+b1) -> elu(@w2+b2) -> @w3+b3 -> y fp32 [.,601]
// ---------------------------------------------------------------------------
template <int ALIGNED>
__global__ __launch_bounds__(256, 4)
void mlp_kernel(const char* __restrict__ ys_base, const f16* __restrict__ wpk1,
                const f16* __restrict__ wpk2, const f16* __restrict__ wpk3,
                const float* __restrict__ b1, const float* __restrict__ b2,
                const float* __restrict__ b3, float* __restrict__ y_out) {
    __shared__ f16 abuf[4][16][72];
    const int tid = threadIdx.x, lane = tid & 63, wid = tid >> 6;
    const int l15 = lane & 15, lg = lane >> 4;
    const size_t row0 = (size_t)blockIdx.x * 64 + wid * 16;
    const long STRIDE = ALIGNED ? 512 : 2404;

    // ---- layer 1: [16,256] @ [256,64] ----
    f32x4 acc1[4];
    #pragma unroll
    for (int jt = 0; jt < 4; ++jt) { float b = b1[jt * 16 + l15]; acc1[jt] = (f32x4){b, b, b, b}; }
    #pragma unroll
    for (int kt = 0; kt < 8; ++kt) {
        f16x8 a;
        const char* src = ys_base + (row0 + l15) * STRIDE + (size_t)(kt * 32 + lg * 8) * 2;
        if (ALIGNED) a = *(const f16x8*)src;
        else {
            uint32_t u[4]; const uint32_t* sp = (const uint32_t*)src;
            u[0] = sp[0]; u[1] = sp[1]; u[2] = sp[2]; u[3] = sp[3];
            a = *(const f16x8*)u;
        }
        #pragma unroll
        for (int jt = 0; jt < 4; ++jt) {
            f16x8 bf = *(const f16x8*)(wpk1 + ((size_t)(kt * 4 + jt) * 64 + lane) * 8);
            acc1[jt] = __builtin_amdgcn_mfma_f32_16x16x32_f16(a, bf, acc1[jt], 0, 0, 0);
        }
    }
    #pragma unroll
    for (int jt = 0; jt < 4; ++jt)
        #pragma unroll
        for (int r = 0; r < 4; ++r)
            abuf[wid][lg * 4 + r][jt * 16 + l15] = (f16)elu_f(acc1[jt][r]);

    // ---- layer 2: [16,64] @ [64,64] ---- (wave-local LDS transpose; DS in-order per wave)
    f16x8 af[2];
    #pragma unroll
    for (int kt = 0; kt < 2; ++kt) af[kt] = *(const f16x8*)&abuf[wid][l15][kt * 32 + lg * 8];
    f32x4 acc2[4];
    #pragma unroll
    for (int jt = 0; jt < 4; ++jt) { float b = b2[jt * 16 + l15]; acc2[jt] = (f32x4){b, b, b, b}; }
    #pragma unroll
    for (int kt = 0; kt < 2; ++kt)
        #pragma unroll
        for (int jt = 0; jt < 4; ++jt) {
            f16x8 bf = *(const f16x8*)(wpk2 + ((size_t)(kt * 4 + jt) * 64 + lane) * 8);
            acc2[jt] = __builtin_amdgcn_mfma_f32_16x16x32_f16(af[kt], bf, acc2[jt], 0, 0, 0);
        }
    #pragma unroll
    for (int jt = 0; jt < 4; ++jt)
        #pragma unroll
        for (int r = 0; r < 4; ++r)
            abuf[wid][lg * 4 + r][jt * 16 + l15] = (f16)elu_f(acc2[jt][r]);

    // ---- layer 3: [16,64] @ [64,608] with col mask at 601 ----
    #pragma unroll
    for (int kt = 0; kt < 2; ++kt) af[kt] = *(const f16x8*)&abuf[wid][l15][kt * 32 + lg * 8];
    for (int jt = 0; jt < 38; ++jt) {
        int j = jt * 16 + l15;
        float b = (j < 601) ? b3[j] : 0.f;
        f32x4 acc = (f32x4){b, b, b, b};
        f16x8 bf0 = *(const f16x8*)(wpk3 + ((size_t)(0 * 38 + jt) * 64 + lane) * 8);
        f16x8 bf1 = *(const f16x8*)(wpk3 + ((size_t)(1 * 38 + jt) * 64 + lane) * 8);
        acc = __builtin_amdgcn_mfma_f32_16x16x32_f16(af[0], bf0, acc, 0, 0, 0);
        acc = __builtin_amdgcn_mfma_f32_16x16x32_f16(af[1], bf1, acc, 0, 0, 0);
        if (j < 601) {
            #pragma unroll
            for (int r = 0; r < 4; ++r)
                y_out[(row0 + lg * 4 + r) * 601 + j] = acc[r];
        }
    }
}

// ---------------------------------------------------------------------------
extern "C" void kernel_launch(void* const* d_in, const int* in_sizes, int n_in,
                              void* d_out, int out_size, void* d_ws, size_t ws_size,
                              hipStream_t stream) {
    const float* x    = (const float*)d_in[0];
    const float* h0   = (const float*)d_in[1];
    const float* w_ih = (const float*)d_in[2];
    const float* w_hh = (const float*)d_in[3];
    const float* b_ih = (const float*)d_in[4];
    const float* b_hh = (const float*)d_in[5];
    const float* w1   = (const float*)d_in[6];
    const float* b1   = (const float*)d_in[7];
    const float* w2   = (const float*)d_in[8];
    const float* b2   = (const float*)d_in[9];
    const float* w3   = (const float*)d_in[10];
    const float* b3   = (const float*)d_in[11];

    float* y_out  = (float*)d_out;
    float* h1_out = y_out + (size_t)64 * 2048 * 601;   // 78,774,272

    // ws layout: packed weights (512 KB region) + optional ys fp16 buffer
    f16* wpkh = (f16*)d_ws;                                 // 393,216 B
    f16* wpk1 = (f16*)((char*)d_ws + 393216);               //  32,768 B
    f16* wpk2 = (f16*)((char*)d_ws + 425984);               //   8,192 B
    f16* wpk3 = (f16*)((char*)d_ws + 434176);               //  77,824 B
    const size_t YS_OFF = 524288;
    const size_t YS_BYTES = (size_t)131072 * 512;           // 67,108,864
    const bool ws_ok = ws_size >= YS_OFF + YS_BYTES;

    pack_weights<<<125, 256, 0, stream>>>(w_hh, w1, w2, w3, wpkh, wpk1, wpk2, wpk3);

    if (ws_ok) {
        char* ys = (char*)d_ws + YS_OFF;                    // row stride 512 B
        gru_kernel<1><<<128, 512, 0, stream>>>(x, h0, w_ih, b_ih, b_hh, wpkh, ys, h1_out);
        mlp_kernel<1><<<2048, 256, 0, stream>>>(ys, wpk1, wpk2, wpk3, b1, b2, b3, y_out);
    } else {
        // stage ys fp16 inside each y row of d_out (row r at byte r*2404, first 512 B);
        // each MLP wave reads its own ys rows before writing those same y rows.
        char* ys = (char*)d_out;
        gru_kernel<0><<<128, 512, 0, stream>>>(x, h0, w_ih, b_ih, b_hh, wpkh, ys, h1_out);
        mlp_kernel<0><<<2048, 256, 0, stream>>>(ys, wpk1, wpk2, wpk3, b1, b2, b3, y_out);
    }
}

// Round 3
// 641.893 us; speedup vs baseline: 1.0298x; 1.0298x over previous
//
#include <hip/hip_runtime.h>
#include <cstdint>
#include <cstddef>

typedef _Float16 f16;
typedef _Float16 f16x8 __attribute__((ext_vector_type(8)));
typedef float f32x4 __attribute__((ext_vector_type(4)));

#define LOG2E 1.4426950408889634f

__device__ __forceinline__ float fast_rcp(float x) { return __builtin_amdgcn_rcpf(x); }
__device__ __forceinline__ float sigmoid_f(float x) { return fast_rcp(1.f + exp2f(-LOG2E * x)); }
__device__ __forceinline__ float tanh_f(float x)    { return 1.f - 2.f * fast_rcp(1.f + exp2f(2.f * LOG2E * x)); }
__device__ __forceinline__ float elu_f(float x)     { return x > 0.f ? x : exp2f(LOG2E * x) - 1.f; }

// ---------------------------------------------------------------------------
// Weight pre-pack: fp32 -> fp16 MFMA B-fragment order.
// B-frag (16x16x32): lane l holds col j = jt*16 + (l&15), k = kt*32 + (l>>4)*8 + e
// wpkh: [48 jt][8 kt][64 l][8 e]   from w_hh[768][256]   (w_hh[j][k], contiguous k)
// wpk1: [8 kt][4 jt][64][8]        from w1[256][64]      (w1[k][j])
// wpk2: [2 kt][4 jt][64][8]        from w2[64][64]
// wpk3: [2 kt][38 jt][64][8]       from w3[64][601] (pad j>=601 with 0)
// ---------------------------------------------------------------------------
__global__ void pack_weights(const float* __restrict__ w_hh, const float* __restrict__ w1,
                             const float* __restrict__ w2, const float* __restrict__ w3,
                             f16* __restrict__ wpkh, f16* __restrict__ wpk1,
                             f16* __restrict__ wpk2, f16* __restrict__ wpk3) {
    int s = blockIdx.x * 256 + threadIdx.x;   // 32000 slots total
    if (s < 24576) {                            // wpkh
        int l = s & 63, kt = (s >> 6) & 7, jt = s >> 9;
        int j = jt * 16 + (l & 15), k = kt * 32 + (l >> 4) * 8;
        const float* src = w_hh + (size_t)j * 256 + k;
        f16x8 v;
        #pragma unroll
        for (int e = 0; e < 8; ++e) v[e] = (f16)src[e];
        *(f16x8*)(wpkh + (size_t)s * 8) = v;
    } else if (s < 26624) {                     // wpk1
        int q = s - 24576;
        int l = q & 63, jt = (q >> 6) & 3, kt = q >> 8;
        int j = jt * 16 + (l & 15), k = kt * 32 + (l >> 4) * 8;
        f16x8 v;
        #pragma unroll
        for (int e = 0; e < 8; ++e) v[e] = (f16)w1[(size_t)(k + e) * 64 + j];
        *(f16x8*)(wpk1 + (size_t)q * 8) = v;
    } else if (s < 27136) {                     // wpk2
        int q = s - 26624;
        int l = q & 63, jt = (q >> 6) & 3, kt = q >> 8;
        int j = jt * 16 + (l & 15), k = kt * 32 + (l >> 4) * 8;
        f16x8 v;
        #pragma unroll
        for (int e = 0; e < 8; ++e) v[e] = (f16)w2[(size_t)(k + e) * 64 + j];
        *(f16x8*)(wpk2 + (size_t)q * 8) = v;
    } else if (s < 32000) {                     // wpk3
        int q = s - 27136;
        int l = q & 63, rr = q >> 6;
        int jt = rr % 38, kt = rr / 38;
        int j = jt * 16 + (l & 15), k = kt * 32 + (l >> 4) * 8;
        f16x8 v;
        #pragma unroll
        for (int e = 0; e < 8; ++e) v[e] = (j < 601) ? (f16)w3[(size_t)(k + e) * 601 + j] : (f16)0.f;
        *(f16x8*)(wpk3 + (size_t)q * 8) = v;
    }
}

// ---------------------------------------------------------------------------
// GRU scan. One block = 16 batch rows, 512 threads (8 waves), 64 timesteps.
// w_hh in registers: 48 fp16 B-frags/lane = 192 VGPR. Wave wid owns output
// cols {wid*32..+31} of each gate. TWO-PASS over the 16-col sub-tiles:
// only 3 f32x4 accumulators live at a time (12 VGPR, not 24) so the total
// stays ~244 < 256 cap and nothing spills to scratch.
// acc init: r,z gates = b_ih+b_hh (folded); n gate = b_hh only.
// ---------------------------------------------------------------------------
template <int ALIGNED>
__global__ __launch_bounds__(512, 2)
void gru_kernel(const float* __restrict__ x, const float* __restrict__ h0,
                const float* __restrict__ w_ih, const float* __restrict__ b_ih,
                const float* __restrict__ b_hh, const f16* __restrict__ wpkh,
                char* __restrict__ ys_base, float* __restrict__ h1_out) {
    __shared__ f16 h_lds[2][16][264];   // pad 256->264 to spread banks
    __shared__ float x_lds[64][16];

    const int tid = threadIdx.x, lane = tid & 63, wid = tid >> 6;
    const int l15 = lane & 15, lg = lane >> 4;
    const int b0 = blockIdx.x * 16;
    const long STRIDE = ALIGNED ? 512 : 2404;

    // --- persistent W fragments (all static-indexed => VGPR-resident) ---
    f16x8 wf[6][8];
    #pragma unroll
    for (int g = 0; g < 3; ++g)
        #pragma unroll
        for (int sub = 0; sub < 2; ++sub) {
            int jt = g * 16 + wid * 2 + sub;
            #pragma unroll
            for (int kt = 0; kt < 8; ++kt)
                wf[g * 2 + sub][kt] = *(const f16x8*)(wpkh + (((size_t)jt * 8 + kt) * 64 + lane) * 8);
        }

    // per-lane input-path scalars
    float wi[3][2], bacc[3][2], bin[2];
    #pragma unroll
    for (int g = 0; g < 3; ++g)
        #pragma unroll
        for (int sub = 0; sub < 2; ++sub) {
            int j = g * 256 + wid * 32 + sub * 16 + l15;
            wi[g][sub] = w_ih[j];
            bacc[g][sub] = (g < 2) ? (b_ih[j] + b_hh[j]) : b_hh[j];
            if (g == 2) bin[sub] = b_ih[j];
        }

    // fp32 h state for this lane's 8 (row,col) cells
    float hp[2][4];
    #pragma unroll
    for (int sub = 0; sub < 2; ++sub)
        #pragma unroll
        for (int r = 0; r < 4; ++r)
            hp[sub][r] = h0[(size_t)(b0 + lg * 4 + r) * 256 + wid * 32 + sub * 16 + l15];

    // stage h0 -> h_lds[0] (fp16) and full x slice -> x_lds
    {
        int row = tid >> 5, k0 = (tid & 31) * 8;
        const float* src = h0 + (size_t)(b0 + row) * 256 + k0;
        f16x8 v;
        #pragma unroll
        for (int e = 0; e < 8; ++e) v[e] = (f16)src[e];
        *(f16x8*)&h_lds[0][row][k0] = v;
        #pragma unroll
        for (int i = 0; i < 2; ++i) {
            int n = tid + i * 512, tt = n >> 4, bb = n & 15;
            x_lds[tt][bb] = x[(size_t)tt * 2048 + b0 + bb];
        }
    }
    __syncthreads();

    for (int t = 0; t < 64; ++t) {
        const int cur = t & 1, nxt = cur ^ 1;
        f32x4 xv4 = *(const f32x4*)&x_lds[t][lg * 4];

        // two passes: sub-tile 0 (cols +0..15), sub-tile 1 (cols +16..31)
        #pragma unroll
        for (int sub = 0; sub < 2; ++sub) {
            f32x4 acc[3];
            #pragma unroll
            for (int g = 0; g < 3; ++g) {
                float b = bacc[g][sub];
                acc[g] = (f32x4){b, b, b, b};
            }
            #pragma unroll
            for (int kt = 0; kt < 8; ++kt) {
                f16x8 a = *(const f16x8*)&h_lds[cur][l15][kt * 32 + lg * 8];
                #pragma unroll
                for (int g = 0; g < 3; ++g)
                    acc[g] = __builtin_amdgcn_mfma_f32_16x16x32_f16(a, wf[g * 2 + sub][kt], acc[g], 0, 0, 0);
            }
            #pragma unroll
            for (int r = 0; r < 4; ++r) {
                float xv = xv4[r];
                float rg = sigmoid_f(xv * wi[0][sub] + acc[0][r]);
                float zg = sigmoid_f(xv * wi[1][sub] + acc[1][r]);
                float ng = tanh_f(xv * wi[2][sub] + bin[sub] + rg * acc[2][r]);
                float hn = ng + zg * (hp[sub][r] - ng);
                hp[sub][r] = hn;
                h_lds[nxt][lg * 4 + r][wid * 32 + sub * 16 + l15] = (f16)hn;
            }
        }
        __syncthreads();

        // coalesced ys write from h_lds[nxt]; next overwrite of this buffer is
        // step t+2's gate phase, which is behind step t+1's barrier.
        {
            int row = tid >> 5, k0 = (tid & 31) * 8;
            f16x8 v = *(const f16x8*)&h_lds[nxt][row][k0];
            char* dst = ys_base + (size_t)(t * 2048 + b0 + row) * STRIDE + (size_t)k0 * 2;
            if (ALIGNED) {
                *(f16x8*)dst = v;
            } else {
                const uint32_t* u = (const uint32_t*)&v;
                uint32_t* d = (uint32_t*)dst;
                d[0] = u[0]; d[1] = u[1]; d[2] = u[2]; d[3] = u[3];
            }
        }
    }

    // h_last (fp32) -> d_out tail
    #pragma unroll
    for (int sub = 0; sub < 2; ++sub)
        #pragma unroll
        for (int r = 0; r < 4; ++r)
            h1_out[(size_t)(b0 + lg * 4 + r) * 256 + wid * 32 + sub * 16 + l15] = hp[sub][r];
}

// ---------------------------------------------------------------------------
// MLP: rows = T*B = 131072. Block = 4 independent waves x 16 rows.
// ys(fp16) -> elu(@w1+b1) -> elu(@w2+b2) -> @w3+b3 -> y fp32 [.,601]
// Layer-3 output staged in per-wave LDS chunks so global stores are
// 256B-contiguous per instruction (vs 4x64B scattered before).
// ---------------------------------------------------------------------------
template <int ALIGNED>
__global__ __launch_bounds__(256, 3)
void mlp_kernel(const char* __restrict__ ys_base, const f16* __restrict__ wpk1,
                const f16* __restrict__ wpk2, const f16* __restrict__ wpk3,
                const float* __restrict__ b1, const float* __restrict__ b2,
                const float* __restrict__ b3, float* __restrict__ y_out) {
    __shared__ f16 abuf[4][16][72];
    __shared__ float ybuf[4][16][132];   // 132 pad => 2-way (free) banks
    const int tid = threadIdx.x, lane = tid & 63, wid = tid >> 6;
    const int l15 = lane & 15, lg = lane >> 4;
    const size_t row0 = (size_t)blockIdx.x * 64 + wid * 16;
    const long STRIDE = ALIGNED ? 512 : 2404;

    // ---- layer 1: [16,256] @ [256,64] ----
    f32x4 acc1[4];
    #pragma unroll
    for (int jt = 0; jt < 4; ++jt) { float b = b1[jt * 16 + l15]; acc1[jt] = (f32x4){b, b, b, b}; }
    #pragma unroll
    for (int kt = 0; kt < 8; ++kt) {
        f16x8 a;
        const char* src = ys_base + (row0 + l15) * STRIDE + (size_t)(kt * 32 + lg * 8) * 2;
        if (ALIGNED) a = *(const f16x8*)src;
        else {
            uint32_t u[4]; const uint32_t* sp = (const uint32_t*)src;
            u[0] = sp[0]; u[1] = sp[1]; u[2] = sp[2]; u[3] = sp[3];
            a = *(const f16x8*)u;
        }
        #pragma unroll
        for (int jt = 0; jt < 4; ++jt) {
            f16x8 bf = *(const f16x8*)(wpk1 + ((size_t)(kt * 4 + jt) * 64 + lane) * 8);
            acc1[jt] = __builtin_amdgcn_mfma_f32_16x16x32_f16(a, bf, acc1[jt], 0, 0, 0);
        }
    }
    #pragma unroll
    for (int jt = 0; jt < 4; ++jt)
        #pragma unroll
        for (int r = 0; r < 4; ++r)
            abuf[wid][lg * 4 + r][jt * 16 + l15] = (f16)elu_f(acc1[jt][r]);

    // ---- layer 2: [16,64] @ [64,64] ---- (wave-local LDS transpose)
    f16x8 af[2];
    #pragma unroll
    for (int kt = 0; kt < 2; ++kt) af[kt] = *(const f16x8*)&abuf[wid][l15][kt * 32 + lg * 8];
    f32x4 acc2[4];
    #pragma unroll
    for (int jt = 0; jt < 4; ++jt) { float b = b2[jt * 16 + l15]; acc2[jt] = (f32x4){b, b, b, b}; }
    #pragma unroll
    for (int kt = 0; kt < 2; ++kt)
        #pragma unroll
        for (int jt = 0; jt < 4; ++jt) {
            f16x8 bf = *(const f16x8*)(wpk2 + ((size_t)(kt * 4 + jt) * 64 + lane) * 8);
            acc2[jt] = __builtin_amdgcn_mfma_f32_16x16x32_f16(af[kt], bf, acc2[jt], 0, 0, 0);
        }
    #pragma unroll
    for (int jt = 0; jt < 4; ++jt)
        #pragma unroll
        for (int r = 0; r < 4; ++r)
            abuf[wid][lg * 4 + r][jt * 16 + l15] = (f16)elu_f(acc2[jt][r]);

    // ---- layer 3: [16,64] @ [64,608], staged 128-col chunks in LDS ----
    #pragma unroll
    for (int kt = 0; kt < 2; ++kt) af[kt] = *(const f16x8*)&abuf[wid][l15][kt * 32 + lg * 8];
    for (int jc = 0; jc < 5; ++jc) {
        const int njt = (jc < 4) ? 8 : 6;            // 38 jt tiles total
        for (int jt2 = 0; jt2 < njt; ++jt2) {
            int jt = jc * 8 + jt2;
            int j = jt * 16 + l15;
            float b = (j < 601) ? b3[j] : 0.f;
            f32x4 acc = (f32x4){b, b, b, b};
            f16x8 bf0 = *(const f16x8*)(wpk3 + ((size_t)(0 * 38 + jt) * 64 + lane) * 8);
            f16x8 bf1 = *(const f16x8*)(wpk3 + ((size_t)(1 * 38 + jt) * 64 + lane) * 8);
            acc = __builtin_amdgcn_mfma_f32_16x16x32_f16(af[0], bf0, acc, 0, 0, 0);
            acc = __builtin_amdgcn_mfma_f32_16x16x32_f16(af[1], bf1, acc, 0, 0, 0);
            #pragma unroll
            for (int r = 0; r < 4; ++r)
                ybuf[wid][lg * 4 + r][jt2 * 16 + l15] = acc[r];
        }
        // wave-local readback (compiler inserts lgkmcnt for the RAW dep);
        // 64 consecutive dwords per store instruction = 256B contiguous.
        const int ncol = (jc < 4) ? 128 : 89;        // 601 - 512
        for (int r16 = 0; r16 < 16; ++r16) {
            #pragma unroll
            for (int it = 0; it < 2; ++it) {
                int c = it * 64 + lane;
                if (c < ncol)
                    y_out[(row0 + r16) * 601 + jc * 128 + c] = ybuf[wid][r16][c];
            }
        }
    }
}

// ---------------------------------------------------------------------------
extern "C" void kernel_launch(void* const* d_in, const int* in_sizes, int n_in,
                              void* d_out, int out_size, void* d_ws, size_t ws_size,
                              hipStream_t stream) {
    const float* x    = (const float*)d_in[0];
    const float* h0   = (const float*)d_in[1];
    const float* w_ih = (const float*)d_in[2];
    const float* w_hh = (const float*)d_in[3];
    const float* b_ih = (const float*)d_in[4];
    const float* b_hh = (const float*)d_in[5];
    const float* w1   = (const float*)d_in[6];
    const float* b1   = (const float*)d_in[7];
    const float* w2   = (const float*)d_in[8];
    const float* b2   = (const float*)d_in[9];
    const float* w3   = (const float*)d_in[10];
    const float* b3   = (const float*)d_in[11];

    float* y_out  = (float*)d_out;
    float* h1_out = y_out + (size_t)64 * 2048 * 601;   // 78,774,272

    // ws layout: packed weights (512 KB region) + ys fp16 buffer
    f16* wpkh = (f16*)d_ws;                                 // 393,216 B
    f16* wpk1 = (f16*)((char*)d_ws + 393216);               //  32,768 B
    f16* wpk2 = (f16*)((char*)d_ws + 425984);               //   8,192 B
    f16* wpk3 = (f16*)((char*)d_ws + 434176);               //  77,824 B
    const size_t YS_OFF = 524288;
    const size_t YS_BYTES = (size_t)131072 * 512;           // 67,108,864
    const bool ws_ok = ws_size >= YS_OFF + YS_BYTES;

    pack_weights<<<125, 256, 0, stream>>>(w_hh, w1, w2, w3, wpkh, wpk1, wpk2, wpk3);

    if (ws_ok) {
        char* ys = (char*)d_ws + YS_OFF;                    // row stride 512 B
        gru_kernel<1><<<128, 512, 0, stream>>>(x, h0, w_ih, b_ih, b_hh, wpkh, ys, h1_out);
        mlp_kernel<1><<<2048, 256, 0, stream>>>(ys, wpk1, wpk2, wpk3, b1, b2, b3, y_out);
    } else {
        // stage ys fp16 inside each y row of d_out (row r at byte r*2404, first 512 B);
        // each MLP wave reads its own ys rows before writing those same y rows.
        char* ys = (char*)d_out;
        gru_kernel<0><<<128, 512, 0, stream>>>(x, h0, w_ih, b_ih, b_hh, wpkh, ys, h1_out);
        mlp_kernel<0><<<2048, 256, 0, stream>>>(ys, wpk1, wpk2, wpk3, b1, b2, b3, y_out);
    }
}

// Round 4
// 581.845 us; speedup vs baseline: 1.1361x; 1.1032x over previous
//
#include <hip/hip_runtime.h>
#include <cstdint>
#include <cstddef>

typedef _Float16 f16;
typedef _Float16 f16x8 __attribute__((ext_vector_type(8)));
typedef float f32x4 __attribute__((ext_vector_type(4)));

#define LOG2E 1.4426950408889634f

__device__ __forceinline__ float fast_rcp(float x) { return __builtin_amdgcn_rcpf(x); }
__device__ __forceinline__ float sigmoid_f(float x) { return fast_rcp(1.f + exp2f(-LOG2E * x)); }
__device__ __forceinline__ float tanh_f(float x)    { return 1.f - 2.f * fast_rcp(1.f + exp2f(2.f * LOG2E * x)); }
__device__ __forceinline__ float elu_f(float x)     { return x > 0.f ? x : exp2f(LOG2E * x) - 1.f; }

// ---------------------------------------------------------------------------
// Weight pre-pack: fp32 -> fp16 MFMA B-fragment order.
// B-frag (16x16x32): lane l holds col j = jt*16 + (l&15), k = kt*32 + (l>>4)*8 + e
// wpkh: [48 jt][8 kt][64 l][8 e]   from w_hh[768][256]   (w_hh[j][k], contiguous k)
// wpk1: [8 kt][4 jt][64][8]        from w1[256][64]      (w1[k][j])
// wpk2: [2 kt][4 jt][64][8]        from w2[64][64]
// wpk3: [2 kt][38 jt][64][8]       from w3[64][601] (pad j>=601 with 0)
// ---------------------------------------------------------------------------
__global__ void pack_weights(const float* __restrict__ w_hh, const float* __restrict__ w1,
                             const float* __restrict__ w2, const float* __restrict__ w3,
                             f16* __restrict__ wpkh, f16* __restrict__ wpk1,
                             f16* __restrict__ wpk2, f16* __restrict__ wpk3) {
    int s = blockIdx.x * 256 + threadIdx.x;   // 32000 slots total
    if (s < 24576) {                            // wpkh
        int l = s & 63, kt = (s >> 6) & 7, jt = s >> 9;
        int j = jt * 16 + (l & 15), k = kt * 32 + (l >> 4) * 8;
        const float* src = w_hh + (size_t)j * 256 + k;
        f16x8 v;
        #pragma unroll
        for (int e = 0; e < 8; ++e) v[e] = (f16)src[e];
        *(f16x8*)(wpkh + (size_t)s * 8) = v;
    } else if (s < 26624) {                     // wpk1
        int q = s - 24576;
        int l = q & 63, jt = (q >> 6) & 3, kt = q >> 8;
        int j = jt * 16 + (l & 15), k = kt * 32 + (l >> 4) * 8;
        f16x8 v;
        #pragma unroll
        for (int e = 0; e < 8; ++e) v[e] = (f16)w1[(size_t)(k + e) * 64 + j];
        *(f16x8*)(wpk1 + (size_t)q * 8) = v;
    } else if (s < 27136) {                     // wpk2
        int q = s - 26624;
        int l = q & 63, jt = (q >> 6) & 3, kt = q >> 8;
        int j = jt * 16 + (l & 15), k = kt * 32 + (l >> 4) * 8;
        f16x8 v;
        #pragma unroll
        for (int e = 0; e < 8; ++e) v[e] = (f16)w2[(size_t)(k + e) * 64 + j];
        *(f16x8*)(wpk2 + (size_t)q * 8) = v;
    } else if (s < 32000) {                     // wpk3
        int q = s - 27136;
        int l = q & 63, rr = q >> 6;
        int jt = rr % 38, kt = rr / 38;
        int j = jt * 16 + (l & 15), k = kt * 32 + (l >> 4) * 8;
        f16x8 v;
        #pragma unroll
        for (int e = 0; e < 8; ++e) v[e] = (j < 601) ? (f16)w3[(size_t)(k + e) * 601 + j] : (f16)0.f;
        *(f16x8*)(wpk3 + (size_t)q * 8) = v;
    }
}

// ---------------------------------------------------------------------------
// GRU scan. One block = 16 batch rows, 512 threads (8 waves), 64 timesteps.
// r,z gate weights in regs (4 frag-sets = 128 VGPR); n-gate weights (131 KB)
// in LDS, streamed per kt. Single pass over kt: A read once, 6 MFMA.
// Register ledger ~206 < 256 cap (launch_bounds(512,2)) => no spill possible.
// acc init: r,z = b_ih+b_hh (folded); n = b_hh only (PyTorch GRU semantics).
// ---------------------------------------------------------------------------
template <int ALIGNED>
__global__ __launch_bounds__(512, 2)
void gru_kernel(const float* __restrict__ x, const float* __restrict__ h0,
                const float* __restrict__ w_ih, const float* __restrict__ b_ih,
                const float* __restrict__ b_hh, const f16* __restrict__ wpkh,
                char* __restrict__ ys_base, float* __restrict__ h1_out) {
    __shared__ f16 h_lds[2][16][264];        // 16,896 B (pad 256->264)
    __shared__ float x_lds[64][16];          //  4,096 B
    __shared__ f16 wn_lds[16][8][64][8];     // 131,072 B: n-gate W, wpkh order

    const int tid = threadIdx.x, lane = tid & 63, wid = tid >> 6;
    const int l15 = lane & 15, lg = lane >> 4;
    const int b0 = blockIdx.x * 16;
    const long STRIDE = ALIGNED ? 512 : 2404;

    // --- r,z W fragments in VGPRs (static-indexed) ---
    f16x8 wf[4][8];
    #pragma unroll
    for (int g = 0; g < 2; ++g)
        #pragma unroll
        for (int sub = 0; sub < 2; ++sub) {
            int jt = g * 16 + wid * 2 + sub;
            #pragma unroll
            for (int kt = 0; kt < 8; ++kt)
                wf[g * 2 + sub][kt] = *(const f16x8*)(wpkh + (((size_t)jt * 8 + kt) * 64 + lane) * 8);
        }

    // --- stage n-gate W (bytes [262144,393216) of wpkh) into LDS, linear ---
    {
        const char* srcW = (const char*)wpkh + 262144;
        char* dstW = (char*)wn_lds;
        #pragma unroll
        for (int i = 0; i < 16; ++i) {
            size_t off = ((size_t)i * 512 + tid) * 16;   // coalesced 16B/lane
            *(f16x8*)(dstW + off) = *(const f16x8*)(srcW + off);
        }
    }

    // per-lane input-path scalars
    float wi[3][2], bacc[3][2], bin[2];
    #pragma unroll
    for (int g = 0; g < 3; ++g)
        #pragma unroll
        for (int sub = 0; sub < 2; ++sub) {
            int j = g * 256 + wid * 32 + sub * 16 + l15;
            wi[g][sub] = w_ih[j];
            bacc[g][sub] = (g < 2) ? (b_ih[j] + b_hh[j]) : b_hh[j];
            if (g == 2) bin[sub] = b_ih[j];
        }

    // fp32 h state for this lane's 8 (row,col) cells
    float hp[2][4];
    #pragma unroll
    for (int sub = 0; sub < 2; ++sub)
        #pragma unroll
        for (int r = 0; r < 4; ++r)
            hp[sub][r] = h0[(size_t)(b0 + lg * 4 + r) * 256 + wid * 32 + sub * 16 + l15];

    // stage h0 -> h_lds[0] (fp16) and full x slice -> x_lds
    {
        int row = tid >> 5, k0 = (tid & 31) * 8;
        const float* src = h0 + (size_t)(b0 + row) * 256 + k0;
        f16x8 v;
        #pragma unroll
        for (int e = 0; e < 8; ++e) v[e] = (f16)src[e];
        *(f16x8*)&h_lds[0][row][k0] = v;
        #pragma unroll
        for (int i = 0; i < 2; ++i) {
            int n = tid + i * 512, tt = n >> 4, bb = n & 15;
            x_lds[tt][bb] = x[(size_t)tt * 2048 + b0 + bb];
        }
    }
    __syncthreads();

    for (int t = 0; t < 64; ++t) {
        const int cur = t & 1, nxt = cur ^ 1;

        f32x4 acc[6];   // [g*2+sub]: 0,1=r; 2,3=z; 4,5=n
        #pragma unroll
        for (int g = 0; g < 3; ++g)
            #pragma unroll
            for (int sub = 0; sub < 2; ++sub) {
                float b = bacc[g][sub];
                acc[g * 2 + sub] = (f32x4){b, b, b, b};
            }

        #pragma unroll
        for (int kt = 0; kt < 8; ++kt) {
            f16x8 a = *(const f16x8*)&h_lds[cur][l15][kt * 32 + lg * 8];
            acc[0] = __builtin_amdgcn_mfma_f32_16x16x32_f16(a, wf[0][kt], acc[0], 0, 0, 0);
            acc[1] = __builtin_amdgcn_mfma_f32_16x16x32_f16(a, wf[1][kt], acc[1], 0, 0, 0);
            acc[2] = __builtin_amdgcn_mfma_f32_16x16x32_f16(a, wf[2][kt], acc[2], 0, 0, 0);
            acc[3] = __builtin_amdgcn_mfma_f32_16x16x32_f16(a, wf[3][kt], acc[3], 0, 0, 0);
            f16x8 bn0 = *(const f16x8*)&wn_lds[wid * 2 + 0][kt][lane][0];
            f16x8 bn1 = *(const f16x8*)&wn_lds[wid * 2 + 1][kt][lane][0];
            acc[4] = __builtin_amdgcn_mfma_f32_16x16x32_f16(a, bn0, acc[4], 0, 0, 0);
            acc[5] = __builtin_amdgcn_mfma_f32_16x16x32_f16(a, bn1, acc[5], 0, 0, 0);
        }

        // gates (lane-local: R/Z/N tiles share the C/D layout)
        f32x4 xv4 = *(const f32x4*)&x_lds[t][lg * 4];
        #pragma unroll
        for (int sub = 0; sub < 2; ++sub)
            #pragma unroll
            for (int r = 0; r < 4; ++r) {
                float xv = xv4[r];
                float rg = sigmoid_f(xv * wi[0][sub] + acc[0 + sub][r]);
                float zg = sigmoid_f(xv * wi[1][sub] + acc[2 + sub][r]);
                float ng = tanh_f(xv * wi[2][sub] + bin[sub] + rg * acc[4 + sub][r]);
                float hn = ng + zg * (hp[sub][r] - ng);
                hp[sub][r] = hn;
                h_lds[nxt][lg * 4 + r][wid * 32 + sub * 16 + l15] = (f16)hn;
            }
        __syncthreads();

        // coalesced ys write from h_lds[nxt]; next overwrite of this buffer is
        // step t+2's gate phase, which is behind step t+1's barrier.
        {
            int row = tid >> 5, k0 = (tid & 31) * 8;
            f16x8 v = *(const f16x8*)&h_lds[nxt][row][k0];
            char* dst = ys_base + (size_t)(t * 2048 + b0 + row) * STRIDE + (size_t)k0 * 2;
            if (ALIGNED) {
                *(f16x8*)dst = v;
            } else {
                const uint32_t* u = (const uint32_t*)&v;
                uint32_t* d = (uint32_t*)dst;
                d[0] = u[0]; d[1] = u[1]; d[2] = u[2]; d[3] = u[3];
            }
        }
    }

    // h_last (fp32) -> d_out tail
    #pragma unroll
    for (int sub = 0; sub < 2; ++sub)
        #pragma unroll
        for (int r = 0; r < 4; ++r)
            h1_out[(size_t)(b0 + lg * 4 + r) * 256 + wid * 32 + sub * 16 + l15] = hp[sub][r];
}

// ---------------------------------------------------------------------------
// MLP: rows = T*B = 131072. Block = 4 independent waves x 16 rows.
// ys(fp16) -> elu(@w1+b1) -> elu(@w2+b2) -> @w3+b3 -> y fp32 [.,601]
// Layer-3 output staged in per-wave LDS chunks => 256B-contiguous stores.
// ---------------------------------------------------------------------------
template <int ALIGNED>
__global__ __launch_bounds__(256, 3)
void mlp_kernel(const char* __restrict__ ys_base, const f16* __restrict__ wpk1,
                const f16* __restrict__ wpk2, const f16* __restrict__ wpk3,
                const float* __restrict__ b1, const float* __restrict__ b2,
                const float* __restrict__ b3, float* __restrict__ y_out) {
    __shared__ f16 abuf[4][16][88];      // pad 64->88: ~2-way banks on r/w
    __shared__ float ybuf[4][16][144];   // pad 128->144: 2-way (free) on write
    const int tid = threadIdx.x, lane = tid & 63, wid = tid >> 6;
    const int l15 = lane & 15, lg = lane >> 4;
    const size_t row0 = (size_t)blockIdx.x * 64 + wid * 16;
    const long STRIDE = ALIGNED ? 512 : 2404;

    // ---- layer 1: [16,256] @ [256,64] ----
    f32x4 acc1[4];
    #pragma unroll
    for (int jt = 0; jt < 4; ++jt) { float b = b1[jt * 16 + l15]; acc1[jt] = (f32x4){b, b, b, b}; }
    #pragma unroll
    for (int kt = 0; kt < 8; ++kt) {
        f16x8 a;
        const char* src = ys_base + (row0 + l15) * STRIDE + (size_t)(kt * 32 + lg * 8) * 2;
        if (ALIGNED) a = *(const f16x8*)src;
        else {
            uint32_t u[4]; const uint32_t* sp = (const uint32_t*)src;
            u[0] = sp[0]; u[1] = sp[1]; u[2] = sp[2]; u[3] = sp[3];
            a = *(const f16x8*)u;
        }
        #pragma unroll
        for (int jt = 0; jt < 4; ++jt) {
            f16x8 bf = *(const f16x8*)(wpk1 + ((size_t)(kt * 4 + jt) * 64 + lane) * 8);
            acc1[jt] = __builtin_amdgcn_mfma_f32_16x16x32_f16(a, bf, acc1[jt], 0, 0, 0);
        }
    }
    #pragma unroll
    for (int jt = 0; jt < 4; ++jt)
        #pragma unroll
        for (int r = 0; r < 4; ++r)
            abuf[wid][lg * 4 + r][jt * 16 + l15] = (f16)elu_f(acc1[jt][r]);

    // ---- layer 2: [16,64] @ [64,64] ---- (wave-local LDS transpose)
    f16x8 af[2];
    #pragma unroll
    for (int kt = 0; kt < 2; ++kt) af[kt] = *(const f16x8*)&abuf[wid][l15][kt * 32 + lg * 8];
    f32x4 acc2[4];
    #pragma unroll
    for (int jt = 0; jt < 4; ++jt) { float b = b2[jt * 16 + l15]; acc2[jt] = (f32x4){b, b, b, b}; }
    #pragma unroll
    for (int kt = 0; kt < 2; ++kt)
        #pragma unroll
        for (int jt = 0; jt < 4; ++jt) {
            f16x8 bf = *(const f16x8*)(wpk2 + ((size_t)(kt * 4 + jt) * 64 + lane) * 8);
            acc2[jt] = __builtin_amdgcn_mfma_f32_16x16x32_f16(af[kt], bf, acc2[jt], 0, 0, 0);
        }
    #pragma unroll
    for (int jt = 0; jt < 4; ++jt)
        #pragma unroll
        for (int r = 0; r < 4; ++r)
            abuf[wid][lg * 4 + r][jt * 16 + l15] = (f16)elu_f(acc2[jt][r]);

    // ---- layer 3: [16,64] @ [64,608], staged 128-col chunks in LDS ----
    #pragma unroll
    for (int kt = 0; kt < 2; ++kt) af[kt] = *(const f16x8*)&abuf[wid][l15][kt * 32 + lg * 8];
    for (int jc = 0; jc < 5; ++jc) {
        const int njt = (jc < 4) ? 8 : 6;            // 38 jt tiles total
        for (int jt2 = 0; jt2 < njt; ++jt2) {
            int jt = jc * 8 + jt2;
            int j = jt * 16 + l15;
            float b = (j < 601) ? b3[j] : 0.f;
            f32x4 acc = (f32x4){b, b, b, b};
            f16x8 bf0 = *(const f16x8*)(wpk3 + ((size_t)(0 * 38 + jt) * 64 + lane) * 8);
            f16x8 bf1 = *(const f16x8*)(wpk3 + ((size_t)(1 * 38 + jt) * 64 + lane) * 8);
            acc = __builtin_amdgcn_mfma_f32_16x16x32_f16(af[0], bf0, acc, 0, 0, 0);
            acc = __builtin_amdgcn_mfma_f32_16x16x32_f16(af[1], bf1, acc, 0, 0, 0);
            #pragma unroll
            for (int r = 0; r < 4; ++r)
                ybuf[wid][lg * 4 + r][jt2 * 16 + l15] = acc[r];
        }
        // wave-local readback; 64 consecutive dwords per store = 256B contiguous
        const int ncol = (jc < 4) ? 128 : 89;        // 601 - 512
        for (int r16 = 0; r16 < 16; ++r16) {
            #pragma unroll
            for (int it = 0; it < 2; ++it) {
                int c = it * 64 + lane;
                if (c < ncol)
                    y_out[(row0 + r16) * 601 + jc * 128 + c] = ybuf[wid][r16][c];
            }
        }
    }
}

// ---------------------------------------------------------------------------
extern "C" void kernel_launch(void* const* d_in, const int* in_sizes, int n_in,
                              void* d_out, int out_size, void* d_ws, size_t ws_size,
                              hipStream_t stream) {
    const float* x    = (const float*)d_in[0];
    const float* h0   = (const float*)d_in[1];
    const float* w_ih = (const float*)d_in[2];
    const float* w_hh = (const float*)d_in[3];
    const float* b_ih = (const float*)d_in[4];
    const float* b_hh = (const float*)d_in[5];
    const float* w1   = (const float*)d_in[6];
    const float* b1   = (const float*)d_in[7];
    const float* w2   = (const float*)d_in[8];
    const float* b2   = (const float*)d_in[9];
    const float* w3   = (const float*)d_in[10];
    const float* b3   = (const float*)d_in[11];

    float* y_out  = (float*)d_out;
    float* h1_out = y_out + (size_t)64 * 2048 * 601;   // 78,774,272

    // ws layout: packed weights (512 KB region) + ys fp16 buffer
    f16* wpkh = (f16*)d_ws;                                 // 393,216 B
    f16* wpk1 = (f16*)((char*)d_ws + 393216);               //  32,768 B
    f16* wpk2 = (f16*)((char*)d_ws + 425984);               //   8,192 B
    f16* wpk3 = (f16*)((char*)d_ws + 434176);               //  77,824 B
    const size_t YS_OFF = 524288;
    const size_t YS_BYTES = (size_t)131072 * 512;           // 67,108,864
    const bool ws_ok = ws_size >= YS_OFF + YS_BYTES;

    pack_weights<<<125, 256, 0, stream>>>(w_hh, w1, w2, w3, wpkh, wpk1, wpk2, wpk3);

    if (ws_ok) {
        char* ys = (char*)d_ws + YS_OFF;                    // row stride 512 B
        gru_kernel<1><<<128, 512, 0, stream>>>(x, h0, w_ih, b_ih, b_hh, wpkh, ys, h1_out);
        mlp_kernel<1><<<2048, 256, 0, stream>>>(ys, wpk1, wpk2, wpk3, b1, b2, b3, y_out);
    } else {
        // stage ys fp16 inside each y row of d_out (row r at byte r*2404, first 512 B);
        // each MLP wave reads its own ys rows before writing those same y rows.
        char* ys = (char*)d_out;
        gru_kernel<0><<<128, 512, 0, stream>>>(x, h0, w_ih, b_ih, b_hh, wpkh, ys, h1_out);
        mlp_kernel<0><<<2048, 256, 0, stream>>>(ys, wpk1, wpk2, wpk3, b1, b2, b3, y_out);
    }
}